// Round 15
// baseline (336.985 us; speedup 1.0000x reference)
//
#include <hip/hip_runtime.h>

typedef unsigned short u16;
typedef unsigned char u8;
typedef unsigned long long u64;
typedef __attribute__((ext_vector_type(8))) short short8;
typedef __attribute__((ext_vector_type(4))) float floatx4;
typedef __attribute__((ext_vector_type(2))) float floatx2;
typedef __attribute__((ext_vector_type(2))) long longx2;
typedef __attribute__((ext_vector_type(4))) unsigned int uintx4;

#define MTOT    16384          // 4 * 64 * 64
#define PADIMG  (66 * 66)      // padded image pixels per batch
#define PADELEM (4 * PADIMG * 256)      // elems per pad buffer (bytes when fp8)
#define WSTEP   (256 * 2304)

__device__ __forceinline__ float bf2f(u16 u) {
  union { unsigned int i; float f; } c; c.i = ((unsigned int)u) << 16; return c.f;
}
__device__ __forceinline__ u16 f2bf(float f) {
  union { float f; unsigned int i; } c; c.f = f;
  unsigned int r = c.i + 0x7FFFu + ((c.i >> 16) & 1u);
  return (u16)(r >> 16);
}
__device__ __forceinline__ u8 f2fp8(float f) {
  return (u8)(__builtin_amdgcn_cvt_pk_fp8_f32(f, f, 0, false) & 0xFF);
}

__device__ __forceinline__ void gl_lds16(const void* g, void* l) {
  __builtin_amdgcn_global_load_lds(
      (const __attribute__((address_space(1))) void*)g,
      (__attribute__((address_space(3))) void*)l, 16, 0, 0);
}

// BK=32 LDS slot (u16 units): 4 chunks/row, XOR with (row>>1)&3  [R4: 0 conflicts]
__device__ __forceinline__ int lds_slot32(int row, int q) {
  return row * 32 + ((q ^ ((row >> 1) & 3)) << 3);
}
// K-permutation within each 64-channel group: original w = ks*32 + q*8 + j
// stored at pos = q*16 + ks*8 + j (so chunk quad = both ks fragments of quad).
// Applied identically to ALL fp8 operands -> dot products invariant.
__device__ __forceinline__ int permw(int w) {
  return ((w >> 3) & 3) * 16 + ((w >> 5) & 1) * 8 + (w & 7);
}
// channel c (0..255) -> K-permuted byte position
__device__ __forceinline__ int permc(int c) {
  return (c & 192) + permw(c & 63);
}

// ---------------------------------------------------------------------------
// merged setup kernel (all regions disjoint):
//   blk < 2304          : pack ALL conv3x3 weights -> fp8 x64, K-permuted.
//                         slots: towers 0..5, dcn 6..7, init-conv 8.
//   blk < 2688 (384)    : pack 1x1 weights -> fp8 x64 K-permuted,
//                         [128 rows zero-padded][256] x3 (init, cls, ref)
//   blk < 3712 (1024)   : features NCHW fp32 -> fp8 K-permuted padded NHWC
//   blk < 5012 (1300)   : zero halo rings of the 5 fp8 padded buffers
//   blk == 5012         : zero GN stats (replaces hipMemsetAsync)
__global__ void setup_all(const float* __restrict__ cls_w, const float* __restrict__ reg_w,
                          const float* __restrict__ initw, const float* __restrict__ clsd,
                          const float* __restrict__ refd,
                          const float* __restrict__ iw, const float* __restrict__ cw,
                          const float* __restrict__ rw,
                          const float* __restrict__ features,
                          u8* __restrict__ wf1,
                          u8* __restrict__ pads8, u8* __restrict__ wf8,
                          float* __restrict__ statsz) {
  int blk = blockIdx.x;
  int t = threadIdx.x;
  if (blk < 2304) {
    int w = blk >> 8;                         // 0..8
    int o = blk & 255;
    const float* src = (w < 3) ? cls_w + (size_t)w * WSTEP
                     : (w < 6) ? reg_w + (size_t)(w - 3) * WSTEP
                     : (w == 6) ? initw : (w == 7) ? clsd : refd;
    __shared__ float wl[2304];
    const float* so = src + (size_t)o * 2304;   // [c][kk] contiguous
    #pragma unroll
    for (int p = 0; p < 9; ++p) wl[p * 256 + t] = so[p * 256 + t];
    __syncthreads();
    if (t < 128) {
      // fp8 e4m3, scaled x64 (std 0.01 is subnormal in e4m3), K-permuted.
      // x64 absorbed by: GN (towers), EP3 rescale (dcn->heads), EP1 (init).
      int slot = (w < 6) ? w : (w == 6) ? 8 : (w - 1);
      u8* dw8 = wf8 + (size_t)slot * WSTEP + (size_t)o * 2304;
      int c = 2 * t;                            // 0..254
      int pos = permc(c);                       // pair stays contiguous (j even)
      #pragma unroll
      for (int p = 0; p < 9; ++p) {
        float f0 = wl[c * 9 + p] * 64.f;
        float f1 = wl[(c + 1) * 9 + p] * 64.f;
        int pk = __builtin_amdgcn_cvt_pk_fp8_f32(f0, f1, 0, false);
        *(u16*)(dw8 + p * 256 + pos) = (u16)(pk & 0xFFFF);
      }
    }
  } else if (blk < 2688) {
    int bb = blk - 2304;                      // 0..383
    int wsel = bb >> 7;
    const float* src = wsel == 0 ? iw : wsel == 1 ? cw : rw;
    int nvalid = wsel == 1 ? 80 : 18;
    int o = bb & 127;
    float v = (o < nvalid) ? src[o * 256 + t] * 64.f : 0.f;
    wf1[(size_t)wsel * 32768 + o * 256 + permc(t)] = f2fp8(v);
  } else if (blk < 3712) {
    __shared__ float tile[64][65];
    int bb = blk - 2688;                      // 0..1023
    int c0 = (bb & 3) * 64;
    int y  = (bb >> 2) & 63;
    int b  = bb >> 8;
    #pragma unroll
    for (int i = 0; i < 16; ++i) {
      int lin = t + i * 256; int c = lin >> 6, x = lin & 63;
      tile[c][x] = features[((b * 256 + c0 + c) * 64 + y) * 64 + x];
    }
    __syncthreads();
    #pragma unroll
    for (int i = 0; i < 8; ++i) {             // 2 fp8 per thread per iter
      int lin = t + i * 256;                  // 0..2047
      int x = lin >> 5, c2 = lin & 31;
      int pk = __builtin_amdgcn_cvt_pk_fp8_f32(tile[2 * c2][x], tile[2 * c2 + 1][x], 0, false);
      *(u16*)(pads8 + (size_t)((b * 66 + y + 1) * 66 + (x + 1)) * 256
              + c0 + permw(2 * c2)) = (u16)pk;
    }
  } else if (blk < 5012) {
    int idx = (blk - 3712) * 256 + t;         // 0..332799 = 5*4*260*64
    int c4 = (idx & 63) << 2;
    int r = idx >> 6;
    int pix = r % 260;
    int ib = r / 260;                         // buf*4 + batch, 0..19
    int y, x;
    if (pix < 66)       { y = 0;  x = pix; }
    else if (pix < 132) { y = 65; x = pix - 66; }
    else if (pix < 196) { y = pix - 132 + 1; x = 0; }
    else                { y = pix - 196 + 1; x = 65; }
    size_t o = (((size_t)ib * PADIMG) + y * 66 + x) * 256 + c4;
    *(unsigned int*)(pads8 + o) = 0u;
  } else {
    #pragma unroll
    for (int i = 0; i < 6; ++i) statsz[t * 6 + i] = 0.f;   // 1536 floats
  }
}

// ---------------------------------------------------------------------------
// paired GroupNorm apply: fp8 staging [2][M][256] bytes (values x64 from fp8
// W; GN is scale-invariant, stats computed fp32-exact in the GEMM) ->
// normalize+affine+relu -> fp8 K-permuted padded NHWC per tower.
// 8 bytes/thread (one 8-ch GN group). grid 4096.
__global__ void __launch_bounds__(256)
gn_apply2(const u8* __restrict__ stage, const float2* __restrict__ st,
          const float* __restrict__ gwc, const float* __restrict__ gbc,
          const float* __restrict__ gwr, const float* __restrict__ gbr,
          u8* __restrict__ cdst8, u8* __restrict__ rdst8) {
  int tid = blockIdx.x * 256 + threadIdx.x;
  int tower = tid >> 19;
  int r = tid & 0x7FFFF;
  int m = r >> 5, c8 = (r & 31) << 3;
  u64 v8 = *(const u64*)(stage + ((size_t)tower << 22) + (size_t)m * 256 + c8);
  unsigned int vlo = (unsigned int)v8, vhi = (unsigned int)(v8 >> 32);
  int b = m >> 12, p = m & 4095, y = p >> 6, x = p & 63;
  float2 ss = st[tower * 128 + b * 32 + (c8 >> 3)];
  float mu = ss.x * (1.f / 32768.f);
  float var = ss.y * (1.f / 32768.f) - mu * mu;
  float rinv = rsqrtf(var + 1e-5f);
  const float* gw = (tower ? gwr : gwc) + c8;
  const float* gb = (tower ? gbr : gbc) + c8;
  floatx2 l0 = __builtin_amdgcn_cvt_pk_f32_fp8(vlo, false);
  floatx2 h0 = __builtin_amdgcn_cvt_pk_f32_fp8(vlo, true);
  floatx2 l1 = __builtin_amdgcn_cvt_pk_f32_fp8(vhi, false);
  floatx2 h1 = __builtin_amdgcn_cvt_pk_f32_fp8(vhi, true);
  float v0 = fmaxf((l0.x - mu) * rinv * gw[0] + gb[0], 0.f);
  float v1 = fmaxf((l0.y - mu) * rinv * gw[1] + gb[1], 0.f);
  float v2 = fmaxf((h0.x - mu) * rinv * gw[2] + gb[2], 0.f);
  float v3 = fmaxf((h0.y - mu) * rinv * gw[3] + gb[3], 0.f);
  float v4 = fmaxf((l1.x - mu) * rinv * gw[4] + gb[4], 0.f);
  float v5 = fmaxf((l1.y - mu) * rinv * gw[5] + gb[5], 0.f);
  float v6 = fmaxf((h1.x - mu) * rinv * gw[6] + gb[6], 0.f);
  float v7 = fmaxf((h1.y - mu) * rinv * gw[7] + gb[7], 0.f);
  size_t pixbase = (size_t)((b * 66 + y + 1) * 66 + (x + 1)) * 256;
  int p0 = __builtin_amdgcn_cvt_pk_fp8_f32(v0, v1, 0, false);
  p0 = __builtin_amdgcn_cvt_pk_fp8_f32(v2, v3, p0, true);
  int p1 = __builtin_amdgcn_cvt_pk_fp8_f32(v4, v5, 0, false);
  p1 = __builtin_amdgcn_cvt_pk_fp8_f32(v6, v7, p1, true);
  u64 o8 = (u64)(unsigned int)p0 | ((u64)(unsigned int)p1 << 32);
  *(u64*)((tower ? rdst8 : cdst8) + pixbase + permc(c8)) = o8;
}

// ---------------------------------------------------------------------------
// bilinear sample, both towers: fp8 K-permuted feats -> fp8 adcn (position-
// preserving; bilinear is channel-agnostic, dcn weights use the same perm).
// 16 lanes/pixel, 16 CONTIGUOUS bytes/lane: one dwordx4 per corner + one 16B
// store per tap. grid 2048.
__global__ void __launch_bounds__(256)
dcn_sample2(const u8* __restrict__ featC, const u8* __restrict__ featR,
            const float* __restrict__ pts,
            u8* __restrict__ AC, u8* __restrict__ AR) {
  int blk = blockIdx.x;
  const u8* featpad = blk < 1024 ? featC : featR;
  u8* A = blk < 1024 ? AC : AR;
  int mblk = blk & 1023;
  int t = threadIdx.x;
  int m = mblk * 16 + (t >> 4);
  int l = t & 15;                       // channels [l*16, l*16+16) (permuted space)
  int b = m >> 12, p = m & 4095, y = p >> 6, x = p & 63;
  const float* pp = pts + (size_t)m * 18;
  const u8* fb = featpad + (size_t)b * PADIMG * 256 + l * 16;
  u8* am = A + (size_t)m * 2304 + l * 16;
  #pragma unroll
  for (int kk = 0; kk < 9; ++kk) {
    float py = (float)y + pp[2 * kk];
    float px = (float)x + pp[2 * kk + 1];
    float fy = floorf(py), fx = floorf(px);
    int y0 = (int)fy, x0 = (int)fx;
    float wy = py - fy, wx = px - fx;
    float w00 = (1.f - wy) * (1.f - wx), w01 = (1.f - wy) * wx;
    float w10 = wy * (1.f - wx), w11 = wy * wx;
    bool yok0 = (unsigned)y0 < 64u, yok1 = (unsigned)(y0 + 1) < 64u;
    bool xok0 = (unsigned)x0 < 64u, xok1 = (unsigned)(x0 + 1) < 64u;
    const u8* base = fb + ((y0 + 1) * 66 + (x0 + 1)) * 256;
    float r[16];
    #pragma unroll
    for (int i = 0; i < 16; ++i) r[i] = 0.f;
    #define ACCUM(OFF, W) { \
      uintx4 v = *(const uintx4*)(base + (OFF)); \
      _Pragma("unroll") \
      for (int e = 0; e < 4; ++e) { \
        floatx2 lo = __builtin_amdgcn_cvt_pk_f32_fp8(v[e], false); \
        floatx2 hi = __builtin_amdgcn_cvt_pk_f32_fp8(v[e], true); \
        r[e*4+0] += (W) * lo.x; r[e*4+1] += (W) * lo.y; \
        r[e*4+2] += (W) * hi.x; r[e*4+3] += (W) * hi.y; } }
    if (yok0 & xok0) ACCUM(0, w00)
    if (yok0 & xok1) ACCUM(256, w01)
    if (yok1 & xok0) ACCUM(66 * 256, w10)
    if (yok1 & xok1) ACCUM(67 * 256, w11)
    #undef ACCUM
    uintx4 o4;
    #pragma unroll
    for (int e = 0; e < 4; ++e) {
      int pk = __builtin_amdgcn_cvt_pk_fp8_f32(r[e*4+0], r[e*4+1], 0, false);
      pk = __builtin_amdgcn_cvt_pk_fp8_f32(r[e*4+2], r[e*4+3], pk, true);
      o4[e] = (unsigned int)pk;
    }
    *(uintx4*)(am + kk * 256) = o4;
  }
}

// ---------------------------------------------------------------------------
// GEMM: C[M,N] = A[M,K] * W[N,K]^T.  128xBN tile, 4 waves.
// [R6-verified source; R8-verified fp8 K-perm layout; R10-verified BK=128.]
// Block decode: [NPAIR==2: pair=blk&1, blk>>=1]  bm=blk&127, bn=blk>>7.
// AMODE 0: flat A; AMODE 1: implicit conv3x3 (pads NHWC).
// FP8 1 (128 BYTES/step): A/W fp8 e4m3, K-PERMUTED per 64-group (permw).
//   Rows of 128 B = 8 x 16B chunks, XOR (row&7); one b128 per (row,h,quad)
//   -> 0 bank conflicts (R8/R10). mfma_f32_16x16x32_fp8_fp8.
// R15: BN=128 for K=2304 convs — resource-sum model (R9/R10 per-step cy):
//   L2-fetch + LDS-read BW dominate; BN=128 halves A-refetch (4x->2x) at
//   TLP cost 4->2 blk/CU. Per-output K-order unchanged -> bit-identical.
// RSH: EP1/EP3 multiply v by 1/(1<<RSH) (undoes fp8 weight x64 chains).
// EP 0: fp8 staging + GN (s,s2) atomics (stats fp32-exact from acc);
// EP 1: relu(v*2^-RSH + bias) -> fp8 K-permuted (init conv -> initf);
// EP 2: relu(v) -> fp8 K-permuted (dcn -> dcnout, keeps x64);
// EP 3: v*2^-RSH + bias (+addpts)(+ptsout) -> fp32 NCHW d_out at cb, gn<nv.
template <int AMODE, int EP, int KSZ, int BN, int BK, int NPAIR, int FP8 = 0, int RSH = 0>
__global__ void __launch_bounds__(256)
gemm_kernel(const u16* __restrict__ A0, const u16* __restrict__ A1,
            const u16* __restrict__ W0, const u16* __restrict__ W1,
            const float* __restrict__ bias0, const float* __restrict__ bias1,
            u16* __restrict__ outb0, u16* __restrict__ outb1,
            float2* __restrict__ st0, float2* __restrict__ st1,
            float* __restrict__ outf,
            const float* __restrict__ addpts0, const float* __restrict__ addpts1,
            float* __restrict__ ptsout0, float* __restrict__ ptsout1,
            int nv0, int nv1, int cb0, int cb1) {
  constexpr int NJ = BN / 32;                 // 16-col accum tiles per wave
  constexpr int ABYT = (FP8 == 1) ? 128 * 128 : 128 * BK * 2;
  constexpr int BBYT = (FP8 == 1) ? BN * 128 : BN * BK * 2;
  __shared__ __align__(16) u8 AsB[ABYT];
  __shared__ __align__(16) u8 BsB[BBYT];
  u16* As = (u16*)AsB;
  u16* Bs = (u16*)BsB;
  int t = threadIdx.x;
  int blk = blockIdx.x;
  int pair = 0;
  if constexpr (NPAIR == 2) { pair = blk & 1; blk >>= 1; }
  const u16* A        = pair ? A1 : A0;
  const u16* Wp       = pair ? W1 : W0;
  const float* bias   = pair ? bias1 : bias0;
  u16* outb           = pair ? outb1 : outb0;
  float2* st          = pair ? st1 : st0;
  const float* addpts = pair ? addpts1 : addpts0;
  float* ptsout       = pair ? ptsout1 : ptsout0;
  int nv = pair ? nv1 : nv0;
  int cb = pair ? cb1 : cb0;

  int bm = blk & 127, bn = blk >> 7;
  int lane = t & 63, wave = t >> 6;
  int wm = (wave & 1) << 6;
  int wn = (wave >> 1) * (BN / 2);
  int quad = lane >> 4, r16 = lane & 15;

  floatx4 acc[4][NJ];
  #pragma unroll
  for (int i = 0; i < 4; ++i)
    #pragma unroll
    for (int j = 0; j < NJ; ++j)
      acc[i][j] = (floatx4){0.f, 0.f, 0.f, 0.f};

  if constexpr (FP8 == 1) {
    // fp8 path, 128 bytes per K-step.
    u8* As8 = AsB;                        // [128 rows][128 B]
    u8* Bs8 = BsB;                        // [BN rows][128 B]
    const u8* A8 = (const u8*)A;
    const u8* W8 = (const u8*)Wp;
    int sub = t >> 3;                     // 0..31
    int cq = (t & 7) ^ (sub & 7);         // XOR-swizzled 16B chunk (8/row)
    int abase[4];
    #pragma unroll
    for (int k = 0; k < 4; ++k) {
      int m = bm * 128 + k * 32 + sub;
      if constexpr (AMODE == 1) {
        int b = m >> 12, p = m & 4095;
        abase[k] = ((b * 66 + (p >> 6)) * 66 + (p & 63)) * 256 + cq * 16;
      } else {
        abase[k] = m * KSZ + cq * 16;
      }
    }
    const u8* wg8 = W8 + (size_t)(bn * BN + sub) * KSZ + cq * 16;

    for (int s = 0; s < KSZ / 128; ++s) {
      int d;
      if constexpr (AMODE == 1) {
        int kk = s >> 1;                 // tap 0..8 (2 steps of 128 B each)
        int c0 = (s & 1) << 7;           // byte offset within 256-B pixel block
        int ky = kk / 3, kx = kk - ky * 3;
        d = ((ky * 66 + kx) << 8) + c0;
      } else {
        d = s * 128;
      }
      #pragma unroll
      for (int k = 0; k < 4; ++k)
        gl_lds16(A8 + abase[k] + d, As8 + k * 4096 + t * 16);
      #pragma unroll
      for (int k = 0; k < BN / 32; ++k)
        gl_lds16(wg8 + (size_t)(k * 32) * KSZ + s * 128, Bs8 + k * 4096 + t * 16);
      __syncthreads();
      long af8[2][2][4], bf8[2][2][NJ];   // [half][ks][·]
      #pragma unroll
      for (int h = 0; h < 2; ++h) {
        #pragma unroll
        for (int i = 0; i < 4; ++i) {
          int row = wm + i * 16 + r16;
          longx2 v = *(const longx2*)&As8[row * 128 + (((h * 4 + quad) ^ (row & 7)) << 4)];
          af8[h][0][i] = v.x; af8[h][1][i] = v.y;
        }
        #pragma unroll
        for (int j = 0; j < NJ; ++j) {
          int row = wn + j * 16 + r16;
          longx2 v = *(const longx2*)&Bs8[row * 128 + (((h * 4 + quad) ^ (row & 7)) << 4)];
          bf8[h][0][j] = v.x; bf8[h][1][j] = v.y;
        }
      }
      #pragma unroll
      for (int h = 0; h < 2; ++h)
        #pragma unroll
        for (int ks = 0; ks < 2; ++ks)
          #pragma unroll
          for (int i = 0; i < 4; ++i)
            #pragma unroll
            for (int j = 0; j < NJ; ++j)
              acc[i][j] = __builtin_amdgcn_mfma_f32_16x16x32_fp8_fp8(
                  af8[h][ks][i], bf8[h][ks][j], acc[i][j], 0, 0, 0);
      __syncthreads();
    }
  } else {
    // BK=32 bf16 path (R4-verified): 4 chunks/row (unused when all-fp8)
    int row = t >> 2;
    int chunkS = (t & 3) ^ ((t >> 3) & 3);
    int m0 = bm * 128 + row, m1 = m0 + 64;
    int abase0, abase1;
    if constexpr (AMODE == 1) {
      int b0 = m0 >> 12, p0 = m0 & 4095;
      int b1 = m1 >> 12, p1 = m1 & 4095;
      abase0 = ((b0 * 66 + (p0 >> 6)) * 66 + (p0 & 63)) * 256 + chunkS * 8;
      abase1 = ((b1 * 66 + (p1 >> 6)) * 66 + (p1 & 63)) * 256 + chunkS * 8;
    } else {
      abase0 = m0 * KSZ + chunkS * 8;
      abase1 = m1 * KSZ + chunkS * 8;
    }
    const u16* wg = Wp + (size_t)(bn * BN + row) * KSZ + chunkS * 8;

    for (int s = 0; s < KSZ / 32; ++s) {
      int d;
      if constexpr (AMODE == 1) {
        int kk = s >> 3;
        int c0 = (s & 7) << 5;
        int ky = kk / 3, kx = kk - ky * 3;
        d = ((ky * 66 + kx) << 8) + c0;
      } else {
        d = s * 32;
      }
      gl_lds16(A + abase0 + d, &As[t * 8]);
      gl_lds16(A + abase1 + d, &As[2048 + t * 8]);
      gl_lds16(wg + s * 32, &Bs[t * 8]);
      if constexpr (BN == 128)
        gl_lds16(wg + (size_t)64 * KSZ + s * 32, &Bs[2048 + t * 8]);
      __syncthreads();
      short8 af[4], bfr[NJ];
      #pragma unroll
      for (int i = 0; i < 4; ++i)
        af[i] = *(const short8*)&As[lds_slot32(wm + i * 16 + r16, quad)];
      #pragma unroll
      for (int j = 0; j < NJ; ++j)
        bfr[j] = *(const short8*)&Bs[lds_slot32(wn + j * 16 + r16, quad)];
      #pragma unroll
      for (int i = 0; i < 4; ++i)
        #pragma unroll
        for (int j = 0; j < NJ; ++j)
          acc[i][j] = __builtin_amdgcn_mfma_f32_16x16x32_bf16(af[i], bfr[j], acc[i][j], 0, 0, 0);
      __syncthreads();
    }
  }

  constexpr float RS = 1.f / (float)(1 << RSH);
  #pragma unroll
  for (int j = 0; j < NJ; ++j) {
    int gn = bn * BN + wn + j * 16 + r16;
    float s = 0.f, s2 = 0.f;
    #pragma unroll
    for (int i = 0; i < 4; ++i) {
      #pragma unroll
      for (int r = 0; r < 4; ++r) {
        int gm = bm * 128 + wm + i * 16 + quad * 4 + r;
        float v = acc[i][j][r];
        if constexpr (EP == 0) {
          ((u8*)outb)[(size_t)gm * 256 + gn] = f2fp8(v);   // fp8 staging
          s += v; s2 += v * v;                             // stats stay exact
        } else if constexpr (EP == 1) {
          if constexpr (RSH > 0) v *= RS;
          float o = fmaxf(v + bias[gn], 0.f);
          if constexpr (FP8 == 1)
            ((u8*)outb)[(size_t)gm * 256 + permc(gn)] = f2fp8(o);
          else
            outb[(size_t)gm * 256 + gn] = f2bf(o);
        } else if constexpr (EP == 2) {
          float o = fmaxf(v, 0.f);
          if constexpr (FP8 == 1)
            ((u8*)outb)[(size_t)gm * 256 + permc(gn)] = f2fp8(o);
          else
            outb[(size_t)gm * 256 + gn] = f2bf(o);
        } else {
          if (gn < nv) {
            if constexpr (RSH > 0) v *= RS;
            v += bias[gn];
            if (addpts) v += addpts[(size_t)gm * 18 + gn];
            if (ptsout) ptsout[(size_t)gm * 18 + gn] = v;
            int bb = gm >> 12, p = gm & 4095;
            outf[(size_t)((bb * 116 + cb + gn) << 12) + p] = v;
          }
        }
      }
    }
    if constexpr (EP == 0) {
      // reduce lanes differing in bits {0,1,2,4,5}; keep bit3 (8-ch group)
      s += __shfl_xor(s, 1);  s2 += __shfl_xor(s2, 1);
      s += __shfl_xor(s, 2);  s2 += __shfl_xor(s2, 2);
      s += __shfl_xor(s, 4);  s2 += __shfl_xor(s2, 4);
      s += __shfl_xor(s, 16); s2 += __shfl_xor(s2, 16);
      s += __shfl_xor(s, 32); s2 += __shfl_xor(s2, 32);
      if ((lane & 55) == 0) {
        float2* sp = st + ((bm >> 5) * 32) + (gn >> 3);
        atomicAdd(&sp->x, s);
        atomicAdd(&sp->y, s2);
      }
    }
  }
}

// ---------------------------------------------------------------------------
extern "C" void kernel_launch(void* const* d_in, const int* in_sizes, int n_in,
                              void* d_out, int out_size, void* d_ws, size_t ws_size,
                              hipStream_t stream) {
  (void)in_sizes; (void)n_in; (void)out_size;
  const float* features    = (const float*)d_in[0];
  const float* cls_w       = (const float*)d_in[1];
  const float* reg_w       = (const float*)d_in[2];
  const float* cls_gn_w    = (const float*)d_in[3];
  const float* cls_gn_b    = (const float*)d_in[4];
  const float* reg_gn_w    = (const float*)d_in[5];
  const float* reg_gn_b    = (const float*)d_in[6];
  const float* init_conv_w = (const float*)d_in[7];
  const float* init_conv_b = (const float*)d_in[8];
  const float* init_out_w  = (const float*)d_in[9];
  const float* init_out_b  = (const float*)d_in[10];
  const float* cls_dcn_w   = (const float*)d_in[11];
  const float* cls_out_w   = (const float*)d_in[12];
  const float* cls_out_b   = (const float*)d_in[13];
  const float* ref_dcn_w   = (const float*)d_in[14];
  const float* ref_out_w   = (const float*)d_in[15];
  const float* ref_out_b   = (const float*)d_in[16];
  float* out = (float*)d_out;

  char* ws = (char*)d_ws;
  size_t off = 0;
  auto alloc = [&](size_t bytes) {
    char* p = ws + off;
    off += (bytes + 255) & ~(size_t)255;
    return p;
  };
  u8*  wf8        = (u8*)alloc((size_t)9 * WSTEP);      // fp8 x64: towers 0..5, dcn 6..7, init 8
  u8*  wf1        = (u8*)alloc((size_t)3 * 32768);      // fp8 x64 K-perm 1x1: init, cls, ref
  // 5 fp8 pads contiguous (halo zeroing indexes across them)
  u8* xpad8       = (u8*)alloc(PADELEM);
  u8* cpadA8      = (u8*)alloc(PADELEM);
  u8* cpadB8      = (u8*)alloc(PADELEM);
  u8* rpadA8      = (u8*)alloc(PADELEM);
  u8* rpadB8      = (u8*)alloc(PADELEM);
  float* ptsbuf   = (float*)alloc((size_t)MTOT * 18 * 4);
  float2* statsAll= (float2*)alloc(3 * 256 * sizeof(float2));
  u8* initf       = (u8*)alloc((size_t)MTOT * 256);     // fp8 K-permuted
  u8* dcnout      = (u8*)alloc((size_t)2 * MTOT * 256); // fp8 K-permuted, x64
  // union region: cstage [2][M][256] fp8 (8.4MB) then adcn [M][2304] fp8 (37.7MB)
  char* unionReg  = alloc((size_t)MTOT * 2304);
  u8* cstage8     = (u8*)unionReg;
  u8* adcn        = (u8*)unionReg;
  u8* adcn2       = (u8*)alloc((size_t)MTOT * 2304);    // only used if ws allows
  bool paired_dcn = (off <= ws_size);

  setup_all<<<5013, 256, 0, stream>>>(cls_w, reg_w, init_conv_w, cls_dcn_w, ref_dcn_w,
                                      init_out_w, cls_out_w, ref_out_w, features,
                                      wf1, xpad8, wf8, (float*)statsAll);

  // towers, paired (cls=pair0, reg=pair1): 3 layers of fp8 conv3x3 (+GN+relu).
  // fp8 W x64 absorbed by GN scale-invariance; staging is fp8 (stats exact).
  // R15: BN=128, grid 512 (2 blk/CU) — halves A-refetch per resource model.
  const u8* curC = xpad8; const u8* curR = xpad8;
  u8* nxtC = cpadA8; u8* altC = cpadB8;
  u8* nxtR = rpadA8; u8* altR = rpadB8;
  for (int i = 0; i < 3; ++i) {
    gemm_kernel<1, 0, 2304, 128, 128, 2, 1><<<512, 256, 0, stream>>>(
        (const u16*)curC, (const u16*)curR,
        (const u16*)(wf8 + (size_t)i * WSTEP), (const u16*)(wf8 + (size_t)(3 + i) * WSTEP),
        nullptr, nullptr, (u16*)cstage8, (u16*)(cstage8 + (size_t)MTOT * 256),
        statsAll + i * 256, statsAll + i * 256 + 128,
        nullptr, nullptr, nullptr, nullptr, nullptr, 0, 0, 0, 0);
    gn_apply2<<<4096, 256, 0, stream>>>(cstage8, statsAll + i * 256,
        cls_gn_w + i * 256, cls_gn_b + i * 256, reg_gn_w + i * 256, reg_gn_b + i * 256,
        nxtC, nxtR);
    curC = nxtC; { u8* tmp = nxtC; nxtC = altC; altC = tmp; }
    curR = nxtR; { u8* tmp = nxtR; nxtR = altR; altR = tmp; }
  }
  const u8* cls_feat8 = curC;   // cpadA8
  const u8* reg_feat8 = curR;   // rpadA8

  // init branch: relu(conv3x3 * 2^-6 + b) -> initf fp8 (K-permuted).
  // R12-measured-best config: BN=32, grid 1024.
  gemm_kernel<1, 1, 2304, 32, 128, 1, 1, 6><<<1024, 256, 0, stream>>>(
      (const u16*)reg_feat8, nullptr, (const u16*)(wf8 + (size_t)8 * WSTEP), nullptr,
      init_conv_b, nullptr, (u16*)initf, nullptr, nullptr, nullptr,
      nullptr, nullptr, nullptr, nullptr, nullptr, 0, 0, 0, 0);
  // 1x1 -> pts_init (out ch 80..97 + ptsbuf). fp8, K=256 -> 2 K-steps.
  // A true-scale, W x64 -> RSH=6. BN=32, 128 cols covered -> grid 512.
  gemm_kernel<0, 3, 256, 32, 128, 1, 1, 6><<<512, 256, 0, stream>>>(
      (const u16*)initf, nullptr, (const u16*)wf1, nullptr,
      init_out_b, nullptr, nullptr, nullptr, nullptr, nullptr, out,
      nullptr, nullptr, ptsbuf, nullptr, 18, 0, 80, 0);

  // dcn conv: fp8 A (sampled fp8 feats) x fp8 W (x64) -> dcnout fp8 (x64 kept).
  // R15: BN=128, grid 512.
  if (paired_dcn) {
    dcn_sample2<<<2048, 256, 0, stream>>>(cls_feat8, reg_feat8, ptsbuf, adcn, adcn2);
    gemm_kernel<0, 2, 2304, 128, 128, 2, 1><<<512, 256, 0, stream>>>(
        (const u16*)adcn, (const u16*)adcn2,
        (const u16*)(wf8 + (size_t)6 * WSTEP), (const u16*)(wf8 + (size_t)7 * WSTEP),
        nullptr, nullptr, (u16*)dcnout, (u16*)(dcnout + (size_t)MTOT * 256), nullptr, nullptr,
        nullptr, nullptr, nullptr, nullptr, nullptr, 0, 0, 0, 0);
  } else {
    dcn_sample2<<<1024, 256, 0, stream>>>(cls_feat8, cls_feat8, ptsbuf, adcn, adcn);
    gemm_kernel<0, 2, 2304, 128, 128, 1, 1><<<256, 256, 0, stream>>>(
        (const u16*)adcn, nullptr, (const u16*)(wf8 + (size_t)6 * WSTEP), nullptr,
        nullptr, nullptr, (u16*)dcnout, nullptr, nullptr, nullptr,
        nullptr, nullptr, nullptr, nullptr, nullptr, 0, 0, 0, 0);
    dcn_sample2<<<1024, 256, 0, stream>>>(reg_feat8, reg_feat8, ptsbuf, adcn, adcn);
    gemm_kernel<0, 2, 2304, 128, 128, 1, 1><<<256, 256, 0, stream>>>(
        (const u16*)adcn, nullptr, (const u16*)(wf8 + (size_t)7 * WSTEP), nullptr,
        nullptr, nullptr, (u16*)(dcnout + (size_t)MTOT * 256), nullptr, nullptr, nullptr,
        nullptr, nullptr, nullptr, nullptr, nullptr, 0, 0, 0, 0);
  }

  // final heads, paired: cls (80 ch at 0), refine (18 ch at 98, + pts_init).
  // fp8: A x64, W x64 -> RSH=12. BN=32, 128 cols, 2 K-steps -> grid 1024.
  gemm_kernel<0, 3, 256, 32, 128, 2, 1, 12><<<1024, 256, 0, stream>>>(
      (const u16*)dcnout, (const u16*)(dcnout + (size_t)MTOT * 256),
      (const u16*)(wf1 + 32768), (const u16*)(wf1 + 65536),
      cls_out_b, ref_out_b, nullptr, nullptr, nullptr, nullptr, out,
      nullptr, ptsbuf, nullptr, nullptr, 80, 18, 0, 98);
}

// Round 16
// 334.336 us; speedup vs baseline: 1.0079x; 1.0079x over previous
//
#include <hip/hip_runtime.h>

typedef unsigned short u16;
typedef unsigned char u8;
typedef unsigned long long u64;
typedef __attribute__((ext_vector_type(8))) short short8;
typedef __attribute__((ext_vector_type(4))) float floatx4;
typedef __attribute__((ext_vector_type(2))) float floatx2;
typedef __attribute__((ext_vector_type(2))) long longx2;
typedef __attribute__((ext_vector_type(4))) unsigned int uintx4;

#define MTOT    16384          // 4 * 64 * 64
#define PADIMG  (66 * 66)      // padded image pixels per batch
#define PADELEM (4 * PADIMG * 256)      // elems per pad buffer (bytes when fp8)
#define WSTEP   (256 * 2304)

__device__ __forceinline__ float bf2f(u16 u) {
  union { unsigned int i; float f; } c; c.i = ((unsigned int)u) << 16; return c.f;
}
__device__ __forceinline__ u16 f2bf(float f) {
  union { float f; unsigned int i; } c; c.f = f;
  unsigned int r = c.i + 0x7FFFu + ((c.i >> 16) & 1u);
  return (u16)(r >> 16);
}
__device__ __forceinline__ u8 f2fp8(float f) {
  return (u8)(__builtin_amdgcn_cvt_pk_fp8_f32(f, f, 0, false) & 0xFF);
}

__device__ __forceinline__ void gl_lds16(const void* g, void* l) {
  __builtin_amdgcn_global_load_lds(
      (const __attribute__((address_space(1))) void*)g,
      (__attribute__((address_space(3))) void*)l, 16, 0, 0);
}

// BK=32 LDS slot (u16 units): 4 chunks/row, XOR with (row>>1)&3  [R4: 0 conflicts]
__device__ __forceinline__ int lds_slot32(int row, int q) {
  return row * 32 + ((q ^ ((row >> 1) & 3)) << 3);
}
// K-permutation within each 64-channel group: original w = ks*32 + q*8 + j
// stored at pos = q*16 + ks*8 + j (so chunk quad = both ks fragments of quad).
// Applied identically to ALL fp8 operands -> dot products invariant.
__device__ __forceinline__ int permw(int w) {
  return ((w >> 3) & 3) * 16 + ((w >> 5) & 1) * 8 + (w & 7);
}
// channel c (0..255) -> K-permuted byte position
__device__ __forceinline__ int permc(int c) {
  return (c & 192) + permw(c & 63);
}

// ---------------------------------------------------------------------------
// merged setup kernel (all regions disjoint):
//   blk < 2304          : pack ALL conv3x3 weights -> fp8 x64, K-permuted.
//                         slots: towers 0..5, dcn 6..7, init-conv 8.
//   blk < 2688 (384)    : pack 1x1 weights -> fp8 x64 K-permuted,
//                         [128 rows zero-padded][256] x3 (init, cls, ref)
//   blk < 3712 (1024)   : features NCHW fp32 -> fp8 K-permuted padded NHWC
//   blk < 5012 (1300)   : zero halo rings of the 5 fp8 padded buffers
//   blk == 5012         : zero GN stats (replaces hipMemsetAsync)
__global__ void setup_all(const float* __restrict__ cls_w, const float* __restrict__ reg_w,
                          const float* __restrict__ initw, const float* __restrict__ clsd,
                          const float* __restrict__ refd,
                          const float* __restrict__ iw, const float* __restrict__ cw,
                          const float* __restrict__ rw,
                          const float* __restrict__ features,
                          u8* __restrict__ wf1,
                          u8* __restrict__ pads8, u8* __restrict__ wf8,
                          float* __restrict__ statsz) {
  int blk = blockIdx.x;
  int t = threadIdx.x;
  if (blk < 2304) {
    int w = blk >> 8;                         // 0..8
    int o = blk & 255;
    const float* src = (w < 3) ? cls_w + (size_t)w * WSTEP
                     : (w < 6) ? reg_w + (size_t)(w - 3) * WSTEP
                     : (w == 6) ? initw : (w == 7) ? clsd : refd;
    __shared__ float wl[2304];
    const float* so = src + (size_t)o * 2304;   // [c][kk] contiguous
    #pragma unroll
    for (int p = 0; p < 9; ++p) wl[p * 256 + t] = so[p * 256 + t];
    __syncthreads();
    if (t < 128) {
      // fp8 e4m3, scaled x64 (std 0.01 is subnormal in e4m3), K-permuted.
      // x64 absorbed by: GN (towers), EP3 rescale (dcn->heads), EP1 (init).
      int slot = (w < 6) ? w : (w == 6) ? 8 : (w - 1);
      u8* dw8 = wf8 + (size_t)slot * WSTEP + (size_t)o * 2304;
      int c = 2 * t;                            // 0..254
      int pos = permc(c);                       // pair stays contiguous (j even)
      #pragma unroll
      for (int p = 0; p < 9; ++p) {
        float f0 = wl[c * 9 + p] * 64.f;
        float f1 = wl[(c + 1) * 9 + p] * 64.f;
        int pk = __builtin_amdgcn_cvt_pk_fp8_f32(f0, f1, 0, false);
        *(u16*)(dw8 + p * 256 + pos) = (u16)(pk & 0xFFFF);
      }
    }
  } else if (blk < 2688) {
    int bb = blk - 2304;                      // 0..383
    int wsel = bb >> 7;
    const float* src = wsel == 0 ? iw : wsel == 1 ? cw : rw;
    int nvalid = wsel == 1 ? 80 : 18;
    int o = bb & 127;
    float v = (o < nvalid) ? src[o * 256 + t] * 64.f : 0.f;
    wf1[(size_t)wsel * 32768 + o * 256 + permc(t)] = f2fp8(v);
  } else if (blk < 3712) {
    __shared__ float tile[64][65];
    int bb = blk - 2688;                      // 0..1023
    int c0 = (bb & 3) * 64;
    int y  = (bb >> 2) & 63;
    int b  = bb >> 8;
    #pragma unroll
    for (int i = 0; i < 16; ++i) {
      int lin = t + i * 256; int c = lin >> 6, x = lin & 63;
      tile[c][x] = features[((b * 256 + c0 + c) * 64 + y) * 64 + x];
    }
    __syncthreads();
    #pragma unroll
    for (int i = 0; i < 8; ++i) {             // 2 fp8 per thread per iter
      int lin = t + i * 256;                  // 0..2047
      int x = lin >> 5, c2 = lin & 31;
      int pk = __builtin_amdgcn_cvt_pk_fp8_f32(tile[2 * c2][x], tile[2 * c2 + 1][x], 0, false);
      *(u16*)(pads8 + (size_t)((b * 66 + y + 1) * 66 + (x + 1)) * 256
              + c0 + permw(2 * c2)) = (u16)pk;
    }
  } else if (blk < 5012) {
    int idx = (blk - 3712) * 256 + t;         // 0..332799 = 5*4*260*64
    int c4 = (idx & 63) << 2;
    int r = idx >> 6;
    int pix = r % 260;
    int ib = r / 260;                         // buf*4 + batch, 0..19
    int y, x;
    if (pix < 66)       { y = 0;  x = pix; }
    else if (pix < 132) { y = 65; x = pix - 66; }
    else if (pix < 196) { y = pix - 132 + 1; x = 0; }
    else                { y = pix - 196 + 1; x = 65; }
    size_t o = (((size_t)ib * PADIMG) + y * 66 + x) * 256 + c4;
    *(unsigned int*)(pads8 + o) = 0u;
  } else {
    #pragma unroll
    for (int i = 0; i < 6; ++i) statsz[t * 6 + i] = 0.f;   // 1536 floats
  }
}

// ---------------------------------------------------------------------------
// paired GroupNorm apply: fp8 staging [2][M][256] bytes (values x64 from fp8
// W; GN is scale-invariant, stats computed fp32-exact in the GEMM) ->
// normalize+affine+relu -> fp8 K-permuted padded NHWC per tower.
// 8 bytes/thread (one 8-ch GN group). grid 4096.
__global__ void __launch_bounds__(256)
gn_apply2(const u8* __restrict__ stage, const float2* __restrict__ st,
          const float* __restrict__ gwc, const float* __restrict__ gbc,
          const float* __restrict__ gwr, const float* __restrict__ gbr,
          u8* __restrict__ cdst8, u8* __restrict__ rdst8) {
  int tid = blockIdx.x * 256 + threadIdx.x;
  int tower = tid >> 19;
  int r = tid & 0x7FFFF;
  int m = r >> 5, c8 = (r & 31) << 3;
  u64 v8 = *(const u64*)(stage + ((size_t)tower << 22) + (size_t)m * 256 + c8);
  unsigned int vlo = (unsigned int)v8, vhi = (unsigned int)(v8 >> 32);
  int b = m >> 12, p = m & 4095, y = p >> 6, x = p & 63;
  float2 ss = st[tower * 128 + b * 32 + (c8 >> 3)];
  float mu = ss.x * (1.f / 32768.f);
  float var = ss.y * (1.f / 32768.f) - mu * mu;
  float rinv = rsqrtf(var + 1e-5f);
  const float* gw = (tower ? gwr : gwc) + c8;
  const float* gb = (tower ? gbr : gbc) + c8;
  floatx2 l0 = __builtin_amdgcn_cvt_pk_f32_fp8(vlo, false);
  floatx2 h0 = __builtin_amdgcn_cvt_pk_f32_fp8(vlo, true);
  floatx2 l1 = __builtin_amdgcn_cvt_pk_f32_fp8(vhi, false);
  floatx2 h1 = __builtin_amdgcn_cvt_pk_f32_fp8(vhi, true);
  float v0 = fmaxf((l0.x - mu) * rinv * gw[0] + gb[0], 0.f);
  float v1 = fmaxf((l0.y - mu) * rinv * gw[1] + gb[1], 0.f);
  float v2 = fmaxf((h0.x - mu) * rinv * gw[2] + gb[2], 0.f);
  float v3 = fmaxf((h0.y - mu) * rinv * gw[3] + gb[3], 0.f);
  float v4 = fmaxf((l1.x - mu) * rinv * gw[4] + gb[4], 0.f);
  float v5 = fmaxf((l1.y - mu) * rinv * gw[5] + gb[5], 0.f);
  float v6 = fmaxf((h1.x - mu) * rinv * gw[6] + gb[6], 0.f);
  float v7 = fmaxf((h1.y - mu) * rinv * gw[7] + gb[7], 0.f);
  size_t pixbase = (size_t)((b * 66 + y + 1) * 66 + (x + 1)) * 256;
  int p0 = __builtin_amdgcn_cvt_pk_fp8_f32(v0, v1, 0, false);
  p0 = __builtin_amdgcn_cvt_pk_fp8_f32(v2, v3, p0, true);
  int p1 = __builtin_amdgcn_cvt_pk_fp8_f32(v4, v5, 0, false);
  p1 = __builtin_amdgcn_cvt_pk_fp8_f32(v6, v7, p1, true);
  u64 o8 = (u64)(unsigned int)p0 | ((u64)(unsigned int)p1 << 32);
  *(u64*)((tower ? rdst8 : cdst8) + pixbase + permc(c8)) = o8;
}

// ---------------------------------------------------------------------------
// bilinear sample, both towers: fp8 K-permuted feats -> fp8 adcn (position-
// preserving; bilinear is channel-agnostic, dcn weights use the same perm).
// 16 lanes/pixel, 16 CONTIGUOUS bytes/lane: one dwordx4 per corner + one 16B
// store per tap. grid 2048.
__global__ void __launch_bounds__(256)
dcn_sample2(const u8* __restrict__ featC, const u8* __restrict__ featR,
            const float* __restrict__ pts,
            u8* __restrict__ AC, u8* __restrict__ AR) {
  int blk = blockIdx.x;
  const u8* featpad = blk < 1024 ? featC : featR;
  u8* A = blk < 1024 ? AC : AR;
  int mblk = blk & 1023;
  int t = threadIdx.x;
  int m = mblk * 16 + (t >> 4);
  int l = t & 15;                       // channels [l*16, l*16+16) (permuted space)
  int b = m >> 12, p = m & 4095, y = p >> 6, x = p & 63;
  const float* pp = pts + (size_t)m * 18;
  const u8* fb = featpad + (size_t)b * PADIMG * 256 + l * 16;
  u8* am = A + (size_t)m * 2304 + l * 16;
  #pragma unroll
  for (int kk = 0; kk < 9; ++kk) {
    float py = (float)y + pp[2 * kk];
    float px = (float)x + pp[2 * kk + 1];
    float fy = floorf(py), fx = floorf(px);
    int y0 = (int)fy, x0 = (int)fx;
    float wy = py - fy, wx = px - fx;
    float w00 = (1.f - wy) * (1.f - wx), w01 = (1.f - wy) * wx;
    float w10 = wy * (1.f - wx), w11 = wy * wx;
    bool yok0 = (unsigned)y0 < 64u, yok1 = (unsigned)(y0 + 1) < 64u;
    bool xok0 = (unsigned)x0 < 64u, xok1 = (unsigned)(x0 + 1) < 64u;
    const u8* base = fb + ((y0 + 1) * 66 + (x0 + 1)) * 256;
    float r[16];
    #pragma unroll
    for (int i = 0; i < 16; ++i) r[i] = 0.f;
    #define ACCUM(OFF, W) { \
      uintx4 v = *(const uintx4*)(base + (OFF)); \
      _Pragma("unroll") \
      for (int e = 0; e < 4; ++e) { \
        floatx2 lo = __builtin_amdgcn_cvt_pk_f32_fp8(v[e], false); \
        floatx2 hi = __builtin_amdgcn_cvt_pk_f32_fp8(v[e], true); \
        r[e*4+0] += (W) * lo.x; r[e*4+1] += (W) * lo.y; \
        r[e*4+2] += (W) * hi.x; r[e*4+3] += (W) * hi.y; } }
    if (yok0 & xok0) ACCUM(0, w00)
    if (yok0 & xok1) ACCUM(256, w01)
    if (yok1 & xok0) ACCUM(66 * 256, w10)
    if (yok1 & xok1) ACCUM(67 * 256, w11)
    #undef ACCUM
    uintx4 o4;
    #pragma unroll
    for (int e = 0; e < 4; ++e) {
      int pk = __builtin_amdgcn_cvt_pk_fp8_f32(r[e*4+0], r[e*4+1], 0, false);
      pk = __builtin_amdgcn_cvt_pk_fp8_f32(r[e*4+2], r[e*4+3], pk, true);
      o4[e] = (unsigned int)pk;
    }
    *(uintx4*)(am + kk * 256) = o4;
  }
}

// ---------------------------------------------------------------------------
// GEMM: C[M,N] = A[M,K] * W[N,K]^T.  128xBN tile, 4 waves.
// [R6-verified source; R8-verified fp8 K-perm layout; R10-verified BK=128.]
// Block decode: [NPAIR==2: pair=blk&1, blk>>=1]  bm=blk&127, bn=blk>>7.
// AMODE 0: flat A; AMODE 1: implicit conv3x3 (pads NHWC).
// FP8 1 (128 BYTES/step): A/W fp8 e4m3, K-PERMUTED per 64-group (permw).
//   Rows of 128 B = 8 x 16B chunks, XOR (row&7); one b128 per (row,h,quad)
//   -> 0 bank conflicts (R8/R10). mfma_f32_16x16x32_fp8_fp8.
// RSH: EP1/EP3 multiply v by 1/(1<<RSH) (undoes fp8 weight x64 chains).
// EP 0: fp8 staging + GN (s,s2) atomics (stats fp32-exact from acc);
// EP 1: relu(v*2^-RSH + bias) -> fp8 K-permuted (init conv -> initf);
// EP 2: relu(v) -> fp8 K-permuted (dcn -> dcnout, keeps x64);
// EP 3: v*2^-RSH + bias (+addpts)(+ptsout) -> fp32 NCHW d_out at cb, gn<nv.
// [Session plateau evidence: K=2304 dispatches pin at ~44.5us across BN in
//  {32,64,128}, BK in {64,128}, dbuf/counted-vmcnt schedules — barrier-
//  serialized K-loop floor; BN=64 is the measured-best config (R14).]
template <int AMODE, int EP, int KSZ, int BN, int BK, int NPAIR, int FP8 = 0, int RSH = 0>
__global__ void __launch_bounds__(256)
gemm_kernel(const u16* __restrict__ A0, const u16* __restrict__ A1,
            const u16* __restrict__ W0, const u16* __restrict__ W1,
            const float* __restrict__ bias0, const float* __restrict__ bias1,
            u16* __restrict__ outb0, u16* __restrict__ outb1,
            float2* __restrict__ st0, float2* __restrict__ st1,
            float* __restrict__ outf,
            const float* __restrict__ addpts0, const float* __restrict__ addpts1,
            float* __restrict__ ptsout0, float* __restrict__ ptsout1,
            int nv0, int nv1, int cb0, int cb1) {
  constexpr int NJ = BN / 32;                 // 16-col accum tiles per wave
  constexpr int ABYT = (FP8 == 1) ? 128 * 128 : 128 * BK * 2;
  constexpr int BBYT = (FP8 == 1) ? BN * 128 : BN * BK * 2;
  __shared__ __align__(16) u8 AsB[ABYT];
  __shared__ __align__(16) u8 BsB[BBYT];
  u16* As = (u16*)AsB;
  u16* Bs = (u16*)BsB;
  int t = threadIdx.x;
  int blk = blockIdx.x;
  int pair = 0;
  if constexpr (NPAIR == 2) { pair = blk & 1; blk >>= 1; }
  const u16* A        = pair ? A1 : A0;
  const u16* Wp       = pair ? W1 : W0;
  const float* bias   = pair ? bias1 : bias0;
  u16* outb           = pair ? outb1 : outb0;
  float2* st          = pair ? st1 : st0;
  const float* addpts = pair ? addpts1 : addpts0;
  float* ptsout       = pair ? ptsout1 : ptsout0;
  int nv = pair ? nv1 : nv0;
  int cb = pair ? cb1 : cb0;

  int bm = blk & 127, bn = blk >> 7;
  int lane = t & 63, wave = t >> 6;
  int wm = (wave & 1) << 6;
  int wn = (wave >> 1) * (BN / 2);
  int quad = lane >> 4, r16 = lane & 15;

  floatx4 acc[4][NJ];
  #pragma unroll
  for (int i = 0; i < 4; ++i)
    #pragma unroll
    for (int j = 0; j < NJ; ++j)
      acc[i][j] = (floatx4){0.f, 0.f, 0.f, 0.f};

  if constexpr (FP8 == 1) {
    // fp8 path, 128 bytes per K-step.
    u8* As8 = AsB;                        // [128 rows][128 B]
    u8* Bs8 = BsB;                        // [BN rows][128 B]
    const u8* A8 = (const u8*)A;
    const u8* W8 = (const u8*)Wp;
    int sub = t >> 3;                     // 0..31
    int cq = (t & 7) ^ (sub & 7);         // XOR-swizzled 16B chunk (8/row)
    int abase[4];
    #pragma unroll
    for (int k = 0; k < 4; ++k) {
      int m = bm * 128 + k * 32 + sub;
      if constexpr (AMODE == 1) {
        int b = m >> 12, p = m & 4095;
        abase[k] = ((b * 66 + (p >> 6)) * 66 + (p & 63)) * 256 + cq * 16;
      } else {
        abase[k] = m * KSZ + cq * 16;
      }
    }
    const u8* wg8 = W8 + (size_t)(bn * BN + sub) * KSZ + cq * 16;

    for (int s = 0; s < KSZ / 128; ++s) {
      int d;
      if constexpr (AMODE == 1) {
        int kk = s >> 1;                 // tap 0..8 (2 steps of 128 B each)
        int c0 = (s & 1) << 7;           // byte offset within 256-B pixel block
        int ky = kk / 3, kx = kk - ky * 3;
        d = ((ky * 66 + kx) << 8) + c0;
      } else {
        d = s * 128;
      }
      #pragma unroll
      for (int k = 0; k < 4; ++k)
        gl_lds16(A8 + abase[k] + d, As8 + k * 4096 + t * 16);
      #pragma unroll
      for (int k = 0; k < BN / 32; ++k)
        gl_lds16(wg8 + (size_t)(k * 32) * KSZ + s * 128, Bs8 + k * 4096 + t * 16);
      __syncthreads();
      long af8[2][2][4], bf8[2][2][NJ];   // [half][ks][·]
      #pragma unroll
      for (int h = 0; h < 2; ++h) {
        #pragma unroll
        for (int i = 0; i < 4; ++i) {
          int row = wm + i * 16 + r16;
          longx2 v = *(const longx2*)&As8[row * 128 + (((h * 4 + quad) ^ (row & 7)) << 4)];
          af8[h][0][i] = v.x; af8[h][1][i] = v.y;
        }
        #pragma unroll
        for (int j = 0; j < NJ; ++j) {
          int row = wn + j * 16 + r16;
          longx2 v = *(const longx2*)&Bs8[row * 128 + (((h * 4 + quad) ^ (row & 7)) << 4)];
          bf8[h][0][j] = v.x; bf8[h][1][j] = v.y;
        }
      }
      #pragma unroll
      for (int h = 0; h < 2; ++h)
        #pragma unroll
        for (int ks = 0; ks < 2; ++ks)
          #pragma unroll
          for (int i = 0; i < 4; ++i)
            #pragma unroll
            for (int j = 0; j < NJ; ++j)
              acc[i][j] = __builtin_amdgcn_mfma_f32_16x16x32_fp8_fp8(
                  af8[h][ks][i], bf8[h][ks][j], acc[i][j], 0, 0, 0);
      __syncthreads();
    }
  } else {
    // BK=32 bf16 path (R4-verified): 4 chunks/row (unused when all-fp8)
    int row = t >> 2;
    int chunkS = (t & 3) ^ ((t >> 3) & 3);
    int m0 = bm * 128 + row, m1 = m0 + 64;
    int abase0, abase1;
    if constexpr (AMODE == 1) {
      int b0 = m0 >> 12, p0 = m0 & 4095;
      int b1 = m1 >> 12, p1 = m1 & 4095;
      abase0 = ((b0 * 66 + (p0 >> 6)) * 66 + (p0 & 63)) * 256 + chunkS * 8;
      abase1 = ((b1 * 66 + (p1 >> 6)) * 66 + (p1 & 63)) * 256 + chunkS * 8;
    } else {
      abase0 = m0 * KSZ + chunkS * 8;
      abase1 = m1 * KSZ + chunkS * 8;
    }
    const u16* wg = Wp + (size_t)(bn * BN + row) * KSZ + chunkS * 8;

    for (int s = 0; s < KSZ / 32; ++s) {
      int d;
      if constexpr (AMODE == 1) {
        int kk = s >> 3;
        int c0 = (s & 7) << 5;
        int ky = kk / 3, kx = kk - ky * 3;
        d = ((ky * 66 + kx) << 8) + c0;
      } else {
        d = s * 32;
      }
      gl_lds16(A + abase0 + d, &As[t * 8]);
      gl_lds16(A + abase1 + d, &As[2048 + t * 8]);
      gl_lds16(wg + s * 32, &Bs[t * 8]);
      if constexpr (BN == 128)
        gl_lds16(wg + (size_t)64 * KSZ + s * 32, &Bs[2048 + t * 8]);
      __syncthreads();
      short8 af[4], bfr[NJ];
      #pragma unroll
      for (int i = 0; i < 4; ++i)
        af[i] = *(const short8*)&As[lds_slot32(wm + i * 16 + r16, quad)];
      #pragma unroll
      for (int j = 0; j < NJ; ++j)
        bfr[j] = *(const short8*)&Bs[lds_slot32(wn + j * 16 + r16, quad)];
      #pragma unroll
      for (int i = 0; i < 4; ++i)
        #pragma unroll
        for (int j = 0; j < NJ; ++j)
          acc[i][j] = __builtin_amdgcn_mfma_f32_16x16x32_bf16(af[i], bfr[j], acc[i][j], 0, 0, 0);
      __syncthreads();
    }
  }

  constexpr float RS = 1.f / (float)(1 << RSH);
  #pragma unroll
  for (int j = 0; j < NJ; ++j) {
    int gn = bn * BN + wn + j * 16 + r16;
    float s = 0.f, s2 = 0.f;
    #pragma unroll
    for (int i = 0; i < 4; ++i) {
      #pragma unroll
      for (int r = 0; r < 4; ++r) {
        int gm = bm * 128 + wm + i * 16 + quad * 4 + r;
        float v = acc[i][j][r];
        if constexpr (EP == 0) {
          ((u8*)outb)[(size_t)gm * 256 + gn] = f2fp8(v);   // fp8 staging
          s += v; s2 += v * v;                             // stats stay exact
        } else if constexpr (EP == 1) {
          if constexpr (RSH > 0) v *= RS;
          float o = fmaxf(v + bias[gn], 0.f);
          if constexpr (FP8 == 1)
            ((u8*)outb)[(size_t)gm * 256 + permc(gn)] = f2fp8(o);
          else
            outb[(size_t)gm * 256 + gn] = f2bf(o);
        } else if constexpr (EP == 2) {
          float o = fmaxf(v, 0.f);
          if constexpr (FP8 == 1)
            ((u8*)outb)[(size_t)gm * 256 + permc(gn)] = f2fp8(o);
          else
            outb[(size_t)gm * 256 + gn] = f2bf(o);
        } else {
          if (gn < nv) {
            if constexpr (RSH > 0) v *= RS;
            v += bias[gn];
            if (addpts) v += addpts[(size_t)gm * 18 + gn];
            if (ptsout) ptsout[(size_t)gm * 18 + gn] = v;
            int bb = gm >> 12, p = gm & 4095;
            outf[(size_t)((bb * 116 + cb + gn) << 12) + p] = v;
          }
        }
      }
    }
    if constexpr (EP == 0) {
      // reduce lanes differing in bits {0,1,2,4,5}; keep bit3 (8-ch group)
      s += __shfl_xor(s, 1);  s2 += __shfl_xor(s2, 1);
      s += __shfl_xor(s, 2);  s2 += __shfl_xor(s2, 2);
      s += __shfl_xor(s, 4);  s2 += __shfl_xor(s2, 4);
      s += __shfl_xor(s, 16); s2 += __shfl_xor(s2, 16);
      s += __shfl_xor(s, 32); s2 += __shfl_xor(s2, 32);
      if ((lane & 55) == 0) {
        float2* sp = st + ((bm >> 5) * 32) + (gn >> 3);
        atomicAdd(&sp->x, s);
        atomicAdd(&sp->y, s2);
      }
    }
  }
}

// ---------------------------------------------------------------------------
extern "C" void kernel_launch(void* const* d_in, const int* in_sizes, int n_in,
                              void* d_out, int out_size, void* d_ws, size_t ws_size,
                              hipStream_t stream) {
  (void)in_sizes; (void)n_in; (void)out_size;
  const float* features    = (const float*)d_in[0];
  const float* cls_w       = (const float*)d_in[1];
  const float* reg_w       = (const float*)d_in[2];
  const float* cls_gn_w    = (const float*)d_in[3];
  const float* cls_gn_b    = (const float*)d_in[4];
  const float* reg_gn_w    = (const float*)d_in[5];
  const float* reg_gn_b    = (const float*)d_in[6];
  const float* init_conv_w = (const float*)d_in[7];
  const float* init_conv_b = (const float*)d_in[8];
  const float* init_out_w  = (const float*)d_in[9];
  const float* init_out_b  = (const float*)d_in[10];
  const float* cls_dcn_w   = (const float*)d_in[11];
  const float* cls_out_w   = (const float*)d_in[12];
  const float* cls_out_b   = (const float*)d_in[13];
  const float* ref_dcn_w   = (const float*)d_in[14];
  const float* ref_out_w   = (const float*)d_in[15];
  const float* ref_out_b   = (const float*)d_in[16];
  float* out = (float*)d_out;

  char* ws = (char*)d_ws;
  size_t off = 0;
  auto alloc = [&](size_t bytes) {
    char* p = ws + off;
    off += (bytes + 255) & ~(size_t)255;
    return p;
  };
  u8*  wf8        = (u8*)alloc((size_t)9 * WSTEP);      // fp8 x64: towers 0..5, dcn 6..7, init 8
  u8*  wf1        = (u8*)alloc((size_t)3 * 32768);      // fp8 x64 K-perm 1x1: init, cls, ref
  // 5 fp8 pads contiguous (halo zeroing indexes across them)
  u8* xpad8       = (u8*)alloc(PADELEM);
  u8* cpadA8      = (u8*)alloc(PADELEM);
  u8* cpadB8      = (u8*)alloc(PADELEM);
  u8* rpadA8      = (u8*)alloc(PADELEM);
  u8* rpadB8      = (u8*)alloc(PADELEM);
  float* ptsbuf   = (float*)alloc((size_t)MTOT * 18 * 4);
  float2* statsAll= (float2*)alloc(3 * 256 * sizeof(float2));
  u8* initf       = (u8*)alloc((size_t)MTOT * 256);     // fp8 K-permuted
  u8* dcnout      = (u8*)alloc((size_t)2 * MTOT * 256); // fp8 K-permuted, x64
  // union region: cstage [2][M][256] fp8 (8.4MB) then adcn [M][2304] fp8 (37.7MB)
  char* unionReg  = alloc((size_t)MTOT * 2304);
  u8* cstage8     = (u8*)unionReg;
  u8* adcn        = (u8*)unionReg;
  u8* adcn2       = (u8*)alloc((size_t)MTOT * 2304);    // only used if ws allows
  bool paired_dcn = (off <= ws_size);

  setup_all<<<5013, 256, 0, stream>>>(cls_w, reg_w, init_conv_w, cls_dcn_w, ref_dcn_w,
                                      init_out_w, cls_out_w, ref_out_w, features,
                                      wf1, xpad8, wf8, (float*)statsAll);

  // towers, paired (cls=pair0, reg=pair1): 3 layers of fp8 conv3x3 (+GN+relu).
  // fp8 W x64 absorbed by GN scale-invariance; staging is fp8 (stats exact).
  // BN=64 grid 1024 = R14 measured-best (BN=128 R15: neutral, reverted).
  const u8* curC = xpad8; const u8* curR = xpad8;
  u8* nxtC = cpadA8; u8* altC = cpadB8;
  u8* nxtR = rpadA8; u8* altR = rpadB8;
  for (int i = 0; i < 3; ++i) {
    gemm_kernel<1, 0, 2304, 64, 128, 2, 1><<<1024, 256, 0, stream>>>(
        (const u16*)curC, (const u16*)curR,
        (const u16*)(wf8 + (size_t)i * WSTEP), (const u16*)(wf8 + (size_t)(3 + i) * WSTEP),
        nullptr, nullptr, (u16*)cstage8, (u16*)(cstage8 + (size_t)MTOT * 256),
        statsAll + i * 256, statsAll + i * 256 + 128,
        nullptr, nullptr, nullptr, nullptr, nullptr, 0, 0, 0, 0);
    gn_apply2<<<4096, 256, 0, stream>>>(cstage8, statsAll + i * 256,
        cls_gn_w + i * 256, cls_gn_b + i * 256, reg_gn_w + i * 256, reg_gn_b + i * 256,
        nxtC, nxtR);
    curC = nxtC; { u8* tmp = nxtC; nxtC = altC; altC = tmp; }
    curR = nxtR; { u8* tmp = nxtR; nxtR = altR; altR = tmp; }
  }
  const u8* cls_feat8 = curC;   // cpadA8
  const u8* reg_feat8 = curR;   // rpadA8

  // init branch: relu(conv3x3 * 2^-6 + b) -> initf fp8 (K-permuted).
  // R12-measured-best config: BN=32, grid 1024.
  gemm_kernel<1, 1, 2304, 32, 128, 1, 1, 6><<<1024, 256, 0, stream>>>(
      (const u16*)reg_feat8, nullptr, (const u16*)(wf8 + (size_t)8 * WSTEP), nullptr,
      init_conv_b, nullptr, (u16*)initf, nullptr, nullptr, nullptr,
      nullptr, nullptr, nullptr, nullptr, nullptr, 0, 0, 0, 0);
  // 1x1 -> pts_init (out ch 80..97 + ptsbuf). fp8, K=256 -> 2 K-steps.
  // A true-scale, W x64 -> RSH=6. BN=32, 128 cols covered -> grid 512.
  gemm_kernel<0, 3, 256, 32, 128, 1, 1, 6><<<512, 256, 0, stream>>>(
      (const u16*)initf, nullptr, (const u16*)wf1, nullptr,
      init_out_b, nullptr, nullptr, nullptr, nullptr, nullptr, out,
      nullptr, nullptr, ptsbuf, nullptr, 18, 0, 80, 0);

  // dcn conv: fp8 A (sampled fp8 feats) x fp8 W (x64) -> dcnout fp8 (x64 kept).
  // BN=64 grid 1024 = R14 measured-best.
  if (paired_dcn) {
    dcn_sample2<<<2048, 256, 0, stream>>>(cls_feat8, reg_feat8, ptsbuf, adcn, adcn2);
    gemm_kernel<0, 2, 2304, 64, 128, 2, 1><<<1024, 256, 0, stream>>>(
        (const u16*)adcn, (const u16*)adcn2,
        (const u16*)(wf8 + (size_t)6 * WSTEP), (const u16*)(wf8 + (size_t)7 * WSTEP),
        nullptr, nullptr, (u16*)dcnout, (u16*)(dcnout + (size_t)MTOT * 256), nullptr, nullptr,
        nullptr, nullptr, nullptr, nullptr, nullptr, 0, 0, 0, 0);
  } else {
    dcn_sample2<<<1024, 256, 0, stream>>>(cls_feat8, cls_feat8, ptsbuf, adcn, adcn);
    gemm_kernel<0, 2, 2304, 64, 128, 1, 1><<<512, 256, 0, stream>>>(
        (const u16*)adcn, nullptr, (const u16*)(wf8 + (size_t)6 * WSTEP), nullptr,
        nullptr, nullptr, (u16*)dcnout, nullptr, nullptr, nullptr,
        nullptr, nullptr, nullptr, nullptr, nullptr, 0, 0, 0, 0);
    dcn_sample2<<<1024, 256, 0, stream>>>(reg_feat8, reg_feat8, ptsbuf, adcn, adcn);
    gemm_kernel<0, 2, 2304, 64, 128, 1, 1><<<512, 256, 0, stream>>>(
        (const u16*)adcn, nullptr, (const u16*)(wf8 + (size_t)7 * WSTEP), nullptr,
        nullptr, nullptr, (u16*)(dcnout + (size_t)MTOT * 256), nullptr, nullptr, nullptr,
        nullptr, nullptr, nullptr, nullptr, nullptr, 0, 0, 0, 0);
  }

  // final heads, paired: cls (80 ch at 0), refine (18 ch at 98, + pts_init).
  // fp8: A x64, W x64 -> RSH=12. BN=32, 128 cols, 2 K-steps -> grid 1024.
  gemm_kernel<0, 3, 256, 32, 128, 2, 1, 12><<<1024, 256, 0, stream>>>(
      (const u16*)dcnout, (const u16*)(dcnout + (size_t)MTOT * 256),
      (const u16*)(wf1 + 32768), (const u16*)(wf1 + 65536),
      cls_out_b, ref_out_b, nullptr, nullptr, nullptr, nullptr, out,
      nullptr, ptsbuf, nullptr, nullptr, 80, 18, 0, 98);
}